// Round 10
// baseline (9382.343 us; speedup 1.0000x reference)
//
#include <hip/hip_runtime.h>
#include <cmath>

#define NB   256
#define NT   64
#define DATA 256
#define DD   264
#define WID  256
#define NSUB 4
#define NTH  512
#define PI_F 3.14159265358979323846f

// ---- d_ws word offsets ----
#define WS_W1T  0                        // fp32 [256][256] k-major W1
#define WS_W2T  (WS_W1T + 65536)         // fp32 [256][256] k-major W2
#define WS_W0B  (WS_W2T + 65536)         // u32 [272][128]: bf16-pair W0T (pad rows 0)
#define WS_W1HB (WS_W0B + 272 * 128)     // u32 [128][128]: bf16-pair W1T rows 128..255
#define WS_W3B  (WS_W1HB + 128 * 128)    // u32 [256][128]: bf16-pair W3T cols 0..255
#define WS_W3TL (WS_W3B + 256 * 128)     // u32 [8][128]:  bf16-pair W3 tail [jt][k]

// ---- LDS word offsets ----
#define L_W1LO 0                         // fp32 [128][256] W1T rows 0..127
#define L_PS   (L_W1LO + 128 * 256)      // fp32 [8][272]
#define L_W3TL (L_PS + 8 * 272)          // u32 [8][128]
#define L_Y    (L_W3TL + 1024)           // 272 (pads 0)
#define L_IN   (L_Y + 272)               // 272 (pads 0)
#define L_ACC  (L_IN + 272)
#define L_HA   (L_ACC + 272)
#define L_HB   (L_HA + 272)
#define L_B0   (L_HB + 272)              // 256
#define L_B1   (L_B0 + 256)              // 256
#define L_B2   (L_B1 + 256)              // 256
#define L_B3   (L_B2 + 256)              // 272
#define LDS_FLOATS (L_B3 + 272)          // 38368 words = 153,472 B -> 1 block/CU

#define FMA4(acc, wv, fk)                                                     \
  acc.x = fmaf((wv).x, (fk), acc.x);                                          \
  acc.y = fmaf((wv).y, (fk), acc.y);                                          \
  acc.z = fmaf((wv).z, (fk), acc.z);                                          \
  acc.w = fmaf((wv).w, (fk), acc.w);

// unpack a bf16 pair (lo = low16, hi = high16) into two fp32
#define UPK(u, f0, f1)                                                        \
  const float f0 = __uint_as_float((u) << 16);                                \
  const float f1 = __uint_as_float((u) & 0xffff0000u);

__device__ __forceinline__ unsigned bf16rn(float f) {
  unsigned u = __float_as_uint(f);
  return (u + 0x7fffu + ((u >> 16) & 1u)) >> 16;   // round-to-nearest-even
}
__device__ __forceinline__ unsigned pk2(float lo, float hi) {
  return bf16rn(lo) | (bf16rn(hi) << 16);
}

__global__ void prep(const float* __restrict__ W0, const float* __restrict__ W1,
                     const float* __restrict__ W2, const float* __restrict__ W3,
                     float* __restrict__ wsf) {
  unsigned* wsu = (unsigned*)wsf;
  int tid = blockIdx.x * blockDim.x + threadIdx.x;
  int stride = gridDim.x * blockDim.x;
  for (int i = tid; i < 65536; i += stride) {         // fp32 W1T, W2T
    int k = i >> 8, j = i & 255;
    wsf[WS_W1T + i] = W1[j * 256 + k];
    wsf[WS_W2T + i] = W2[j * 256 + k];
  }
  for (int i = tid; i < 272 * 128; i += stride) {     // W0 bf16 k-major
    int k = i >> 7, m = i & 127;
    float lo = 0.f, hi = 0.f;
    if (k < DD) { lo = W0[(2 * m) * DD + k]; hi = W0[(2 * m + 1) * DD + k]; }
    wsu[WS_W0B + i] = pk2(lo, hi);
  }
  for (int i = tid; i < 128 * 128; i += stride) {     // W1 rows 128..255 bf16
    int k2 = i >> 7, m = i & 127;
    wsu[WS_W1HB + i] = pk2(W1[(2 * m) * 256 + 128 + k2],
                           W1[(2 * m + 1) * 256 + 128 + k2]);
  }
  for (int i = tid; i < 256 * 128; i += stride) {     // W3 cols 0..255 bf16
    int k = i >> 7, m = i & 127;
    wsu[WS_W3B + i] = pk2(W3[(2 * m) * 256 + k], W3[(2 * m + 1) * 256 + k]);
  }
  for (int i = tid; i < 8 * 128; i += stride) {       // W3 tail rows [jt][k]
    int jt = i >> 7, m = i & 127;
    wsu[WS_W3TL + i] = pk2(W3[(256 + jt) * 256 + 2 * m],
                           W3[(256 + jt) * 256 + 2 * m + 1]);
  }
}

// (512,1): block has 8 waves = 2/SIMD minimum -> VGPR cap 256. Demand ~190
// (w2r 128 + stream bufs + working), so no spill. R9's (512,2) forced a
// 128 cap -> w2r spilled to (L2-cached) scratch = hidden 256KB/eval stream.
__global__ __launch_bounds__(NTH, 1) void node_integrate(
    const float* __restrict__ ts, const float* __restrict__ xs,
    const float* __restrict__ a_sample,
    const float* __restrict__ b0g, const float* __restrict__ b1g,
    const float* __restrict__ b2g, const float* __restrict__ b3g,
    const float* __restrict__ ws, float* __restrict__ out) {
  extern __shared__ float sm[];
  unsigned* smu = (unsigned*)sm;
  const unsigned* wsu = (const unsigned*)ws;
  const int b   = blockIdx.x;
  const int tid = threadIdx.x;
  const int w   = tid >> 6;
  const int l   = tid & 63;

  // ---- one-time fills ----
  for (int i = tid; i < 256; i += NTH) {
    sm[L_B0 + i] = b0g[i];
    sm[L_B1 + i] = b1g[i];
    sm[L_B2 + i] = b2g[i];
  }
  for (int i = tid; i < 272; i += NTH) sm[L_B3 + i] = (i < DD) ? b3g[i] : 0.f;
  {
    const float4* src = (const float4*)(ws + WS_W1T);   // rows 0..127
    float4* dst = (float4*)(sm + L_W1LO);
    for (int i = tid; i < 128 * 64; i += NTH) dst[i] = src[i];
  }
  for (int i = tid; i < 1024; i += NTH) smu[L_W3TL + i] = wsu[WS_W3TL + i];
  // W2 register cache: wave w holds k = w + 8i, lane l cols 4l..4l+3 (fp32)
  float4 w2r[32];
  {
    const float4* w2t4 = (const float4*)(ws + WS_W2T);
#pragma unroll
    for (int i = 0; i < 32; ++i) w2r[i] = w2t4[(w + 8 * i) * 64 + l];
  }
  {
    const float sc = a_sample[b] * expf(-0.1f * ts[0]);
    for (int i = tid; i < 272; i += NTH) {
      float v = 0.f;
      if (i < DATA) v = sc * sinf(PI_F * xs[(size_t)b * DATA + i]);
      sm[L_Y + i]  = v;
      sm[L_IN + i] = 0.f;
    }
  }
  __syncthreads();

  if (tid < DATA) out[((size_t)b * NT) * DATA + tid] = sm[L_Y + tid];

  float4* ps4 = (float4*)(sm + L_PS);
  const uint2* w0b = (const uint2*)(wsu + WS_W0B);
  const uint2* w1h = (const uint2*)(wsu + WS_W1HB);
  const uint2* w3b = (const uint2*)(wsu + WS_W3B);

#pragma unroll 1
  for (int t = 0; t < NT - 1; ++t) {
    const float dt = ts[t + 1] - ts[t];
    const float h  = dt * (1.0f / NSUB);
#pragma unroll 1
    for (int sub = 0; sub < NSUB; ++sub) {
#pragma unroll 1
      for (int st = 0; st < 3; ++st) {
        const float* finp = sm + ((st == 0) ? L_Y : L_IN);

        // ---- L0: hA = tanh(W0 @ fin + b0); streamed bf16, K=272(pad)
        {
          float4 acc; acc.x = acc.y = acc.z = acc.w = 0.f;
#pragma unroll 8
          for (int i = 0; i < 34; ++i) {
            const int k = w + 8 * i;            // < 272
            const uint2 u = w0b[k * 64 + l];
            const float fk = finp[k];
            UPK(u.x, c0, c1) UPK(u.y, c2, c3)
            acc.x = fmaf(c0, fk, acc.x); acc.y = fmaf(c1, fk, acc.y);
            acc.z = fmaf(c2, fk, acc.z); acc.w = fmaf(c3, fk, acc.w);
          }
          ps4[w * 68 + l] = acc;
        }
        __syncthreads();
        if (tid < 256) {
          float sv = sm[L_B0 + tid];
#pragma unroll
          for (int ww = 0; ww < 8; ++ww) sv += sm[L_PS + ww * 272 + tid];
          sm[L_HA + tid] = tanhf(sv);
        }
        __syncthreads();

        // ---- L1: hB = tanh(W1 @ hA + b1); k<128 fp32 LDS, k>=128 bf16 stream
        {
          float4 acc; acc.x = acc.y = acc.z = acc.w = 0.f;
          const float4* w1lo4 = (const float4*)(sm + L_W1LO);
#pragma unroll
          for (int i = 0; i < 16; ++i) {
            const int k = w + 8 * i;            // < 128
            const float fk = sm[L_HA + k];
            const float4 wv = w1lo4[k * 64 + l];
            FMA4(acc, wv, fk)
          }
#pragma unroll 8
          for (int i = 0; i < 16; ++i) {
            const int k2 = w + 8 * i;           // row 128+k2
            const uint2 u = w1h[k2 * 64 + l];
            const float fk = sm[L_HA + 128 + k2];
            UPK(u.x, c0, c1) UPK(u.y, c2, c3)
            acc.x = fmaf(c0, fk, acc.x); acc.y = fmaf(c1, fk, acc.y);
            acc.z = fmaf(c2, fk, acc.z); acc.w = fmaf(c3, fk, acc.w);
          }
          ps4[w * 68 + l] = acc;
        }
        __syncthreads();
        if (tid < 256) {
          float sv = sm[L_B1 + tid];
#pragma unroll
          for (int ww = 0; ww < 8; ++ww) sv += sm[L_PS + ww * 272 + tid];
          sm[L_HB + tid] = tanhf(sv);
        }
        __syncthreads();

        // ---- L2: hA = tanh(W2 @ hB + b2); all-register fp32 W2
        {
          float4 acc; acc.x = acc.y = acc.z = acc.w = 0.f;
#pragma unroll
          for (int i = 0; i < 32; ++i) {
            const float fk = sm[L_HB + w + 8 * i];
            FMA4(acc, w2r[i], fk)
          }
          ps4[w * 68 + l] = acc;
        }
        __syncthreads();
        if (tid < 256) {
          float sv = sm[L_B2 + tid];
#pragma unroll
          for (int ww = 0; ww < 8; ++ww) sv += sm[L_PS + ww * 272 + tid];
          sm[L_HA + tid] = tanhf(sv);
        }
        __syncthreads();

        // ---- L3: kv = W3 @ hA + b3; main cols streamed bf16
        {
          float4 acc; acc.x = acc.y = acc.z = acc.w = 0.f;
#pragma unroll 8
          for (int i = 0; i < 32; ++i) {
            const int k = w + 8 * i;
            const uint2 u = w3b[k * 64 + l];
            const float fk = sm[L_HA + k];
            UPK(u.x, c0, c1) UPK(u.y, c2, c3)
            acc.x = fmaf(c0, fk, acc.x); acc.y = fmaf(c1, fk, acc.y);
            acc.z = fmaf(c2, fk, acc.z); acc.w = fmaf(c3, fk, acc.w);
          }
          ps4[w * 68 + l] = acc;
        }
        __syncthreads();
        // reduce + RK: waves 0-3 handle j<256; waves 4-7 compute tail j>=256
        if (tid < 256) {
          float kv = sm[L_B3 + tid];
#pragma unroll
          for (int ww = 0; ww < 8; ++ww) kv += sm[L_PS + ww * 272 + tid];
          if (st == 0) {
            sm[L_ACC + tid] = (2.0f / 9.0f) * kv;
            sm[L_IN + tid]  = sm[L_Y + tid] + 0.5f * h * kv;
          } else if (st == 1) {
            sm[L_ACC + tid] += (1.0f / 3.0f) * kv;
            sm[L_IN + tid]   = sm[L_Y + tid] + 0.75f * h * kv;
          } else {
            sm[L_Y + tid] += h * (sm[L_ACC + tid] + (4.0f / 9.0f) * kv);
          }
        } else {
          const int idx = tid - 256;
          const int jt = idx >> 5, g = idx & 31;
          const uint4* tl = (const uint4*)(smu + L_W3TL);
          const uint4 u = tl[jt * 32 + g];        // k = 8g..8g+7
          float sv;
          {
            UPK(u.x, c0, c1) UPK(u.y, c2, c3)
            UPK(u.z, c4, c5) UPK(u.w, c6, c7)
            const float* ha = sm + L_HA + 8 * g;
            sv = c0 * ha[0] + c1 * ha[1] + c2 * ha[2] + c3 * ha[3] +
                 c4 * ha[4] + c5 * ha[5] + c6 * ha[6] + c7 * ha[7];
          }
          sv += __shfl_xor(sv, 1);  sv += __shfl_xor(sv, 2);
          sv += __shfl_xor(sv, 4);  sv += __shfl_xor(sv, 8);
          sv += __shfl_xor(sv, 16);
          if (g == 0) {
            const int j = 256 + jt;
            const float kv = sv + sm[L_B3 + j];
            if (st == 0) {
              sm[L_ACC + j] = (2.0f / 9.0f) * kv;
              sm[L_IN + j]  = sm[L_Y + j] + 0.5f * h * kv;
            } else if (st == 1) {
              sm[L_ACC + j] += (1.0f / 3.0f) * kv;
              sm[L_IN + j]   = sm[L_Y + j] + 0.75f * h * kv;
            } else {
              sm[L_Y + j] += h * (sm[L_ACC + j] + (4.0f / 9.0f) * kv);
            }
          }
        }
        __syncthreads();
      }
    }
    if (tid < DATA) out[((size_t)b * NT + (t + 1)) * DATA + tid] = sm[L_Y + tid];
  }
}

extern "C" void kernel_launch(void* const* d_in, const int* in_sizes, int n_in,
                              void* d_out, int out_size, void* d_ws, size_t ws_size,
                              hipStream_t stream) {
  const float* ts = (const float*)d_in[0];
  const float* xs = (const float*)d_in[1];
  const float* a  = (const float*)d_in[2];
  const float* W0 = (const float*)d_in[3];
  const float* b0 = (const float*)d_in[4];
  const float* W1 = (const float*)d_in[5];
  const float* b1 = (const float*)d_in[6];
  const float* W2 = (const float*)d_in[7];
  const float* b2 = (const float*)d_in[8];
  const float* W3 = (const float*)d_in[9];
  const float* b3 = (const float*)d_in[10];
  float* ws  = (float*)d_ws;
  float* out = (float*)d_out;

  const size_t lds_bytes = LDS_FLOATS * sizeof(float);
  hipFuncSetAttribute(reinterpret_cast<const void*>(node_integrate),
                      hipFuncAttributeMaxDynamicSharedMemorySize,
                      (int)lds_bytes);

  hipLaunchKernelGGL(prep, dim3(256), dim3(256), 0, stream, W0, W1, W2, W3, ws);
  hipLaunchKernelGGL(node_integrate, dim3(NB), dim3(NTH), lds_bytes, stream,
                     ts, xs, a, b0, b1, b2, b3, ws, out);
}